// Round 1
// baseline (1454.644 us; speedup 1.0000x reference)
//
#include <hip/hip_runtime.h>
#include <hip/hip_bf16.h>

#define BATCH   8
#define CH      64
#define NHEAD   2
#define HDIM    32
#define NPIX    65536          // 256*256
#define TILE_PX 64
#define TILES_PER_BATCH (NPIX / TILE_PX)   // 1024
#define BLOCKS_X 128

__device__ __forceinline__ float phi_f(float t) {
    // elu(t) + 1
    return t > 0.0f ? t + 1.0f : __expf(t);
}

// ---------------- Pass 1: KV[b][h][c][d] = sum_n phi(k)[c,n] * v[d,n] ----------------
__global__ __launch_bounds__(256) void la_pass1(
    const float* __restrict__ x, const float* __restrict__ qkv_w,
    float* __restrict__ kv)
{
    __shared__ __align__(16) float kls[64][68];   // phi(k) [channel][pixel]
    __shared__ __align__(16) float vls[64][68];   // v      [channel][pixel]

    const int t    = threadIdx.x;
    const int b    = blockIdx.y;
    const int lane = t & 63;
    const int wv_  = __builtin_amdgcn_readfirstlane(t >> 6);  // wave id 0..3 (uniform)
    const int isK  = (wv_ < 2);
    const int row0 = (wv_ & 1) * 32;
    // qkv_w rows: q=0..63, k=64..127, v=128..191
    const float* Wb = qkv_w + (size_t)(64 + (wv_ >> 1) * 64 + row0) * 64;
    const float* xb = x + (size_t)b * CH * NPIX;

    // stage-3 ownership: 8 KV entries per thread: head h3, c in {c0,c0+1}, d in {d0..d0+3}
    const int h3 = t >> 7;
    const int c0 = ((t >> 3) & 15) * 2;
    const int d0 = (t & 7) * 4;
    float kvacc[2][4];
    #pragma unroll
    for (int i = 0; i < 2; i++)
        #pragma unroll
        for (int j = 0; j < 4; j++) kvacc[i][j] = 0.0f;

    for (int tile = blockIdx.x; tile < TILES_PER_BATCH; tile += gridDim.x) {
        const int p = tile * TILE_PX + lane;
        const float* xp = xb + p;

        // ---- stage 2: this wave computes 32 output channels (k or v) for its pixel
        float acc[32];
        #pragma unroll
        for (int i = 0; i < 32; i++) acc[i] = 0.0f;

        for (int cc = 0; cc < 64; cc += 16) {
            float xr[16];
            #pragma unroll
            for (int c = 0; c < 16; c++) xr[c] = xp[(size_t)(cc + c) * NPIX];
            const float* Wc = Wb + cc;
            #pragma unroll
            for (int c = 0; c < 16; c++) {
                #pragma unroll
                for (int i = 0; i < 32; i++) {
                    acc[i] += Wc[i * 64 + c] * xr[c];   // weight = wave-uniform s_load
                }
            }
        }

        if (isK) {
            #pragma unroll
            for (int i = 0; i < 32; i++) kls[row0 + i][lane] = phi_f(acc[i]);
        } else {
            #pragma unroll
            for (int i = 0; i < 32; i++) vls[row0 + i][lane] = acc[i];
        }
        __syncthreads();

        // ---- stage 3: block-wide KV accumulation over the 64 pixels in this tile
        {
            const int kr0 = h3 * 32 + c0;
            const int vr0 = h3 * 32 + d0;
            for (int p4 = 0; p4 < 16; p4++) {
                float4 kk[2], vv[4];
                #pragma unroll
                for (int i = 0; i < 2; i++)
                    kk[i] = *reinterpret_cast<const float4*>(&kls[kr0 + i][p4 * 4]);
                #pragma unroll
                for (int j = 0; j < 4; j++)
                    vv[j] = *reinterpret_cast<const float4*>(&vls[vr0 + j][p4 * 4]);
                #pragma unroll
                for (int i = 0; i < 2; i++)
                    #pragma unroll
                    for (int j = 0; j < 4; j++) {
                        kvacc[i][j] += kk[i].x * vv[j].x + kk[i].y * vv[j].y
                                     + kk[i].z * vv[j].z + kk[i].w * vv[j].w;
                    }
            }
        }
        __syncthreads();
    }

    #pragma unroll
    for (int i = 0; i < 2; i++)
        #pragma unroll
        for (int j = 0; j < 4; j++) {
            atomicAdd(&kv[(((size_t)b * NHEAD + h3) * HDIM + (c0 + i)) * HDIM + d0 + j],
                      kvacc[i][j]);
        }
}

// ---------------- Pass 2: y = proj_w * ( KV^T * phi(q) ) ----------------
__global__ __launch_bounds__(256) void la_pass2(
    const float* __restrict__ x, const float* __restrict__ qkv_w,
    const float* __restrict__ proj_w, const float* __restrict__ kv,
    float* __restrict__ y)
{
    __shared__ __align__(16) float qls[64][68];   // phi(q) [channel][pixel]
    __shared__ __align__(16) float ols[64][68];   // attention out [channel][pixel]

    const int t    = threadIdx.x;
    const int b    = blockIdx.y;
    const int lane = t & 63;
    const int wv_  = __builtin_amdgcn_readfirstlane(t >> 6);  // 0..3 uniform
    const int r0   = wv_ * 16;            // this wave's 16-channel block
    const int h    = wv_ >> 1;            // head (stage B)
    const int d0   = (wv_ & 1) * 16;      // d offset within head (stage B)
    const float* Wq  = qkv_w + (size_t)r0 * 64;          // q rows 0..63
    const float* Wp  = proj_w + (size_t)r0 * 64;
    const float* kvb = kv + ((size_t)b * NHEAD + h) * HDIM * HDIM + d0;
    const float* xb  = x + (size_t)b * CH * NPIX;
    float*       yb  = y + (size_t)b * CH * NPIX;

    for (int tile = blockIdx.x; tile < TILES_PER_BATCH; tile += gridDim.x) {
        const int p = tile * TILE_PX + lane;
        const float* xp = xb + p;

        // ---- stage A: q rows r0..r0+15, phi applied
        float acc[16];
        #pragma unroll
        for (int i = 0; i < 16; i++) acc[i] = 0.0f;
        for (int cc = 0; cc < 64; cc += 16) {
            float xr[16];
            #pragma unroll
            for (int c = 0; c < 16; c++) xr[c] = xp[(size_t)(cc + c) * NPIX];
            const float* Wc = Wq + cc;
            #pragma unroll
            for (int c = 0; c < 16; c++) {
                #pragma unroll
                for (int i = 0; i < 16; i++) acc[i] += Wc[i * 64 + c] * xr[c];
            }
        }
        #pragma unroll
        for (int i = 0; i < 16; i++) qls[r0 + i][lane] = phi_f(acc[i]);
        __syncthreads();

        // ---- stage B: out[h*32+d][p] = sum_c qphi[h*32+c][p] * KV[h][c][d]
        float acc2[16];
        #pragma unroll
        for (int i = 0; i < 16; i++) acc2[i] = 0.0f;
        #pragma unroll
        for (int c = 0; c < 32; c++) {
            float qv = qls[h * 32 + c][lane];
            #pragma unroll
            for (int i = 0; i < 16; i++) acc2[i] += qv * kvb[c * HDIM + i];  // uniform s_load
        }
        #pragma unroll
        for (int i = 0; i < 16; i++) ols[r0 + i][lane] = acc2[i];
        __syncthreads();

        // ---- stage C: y rows r0..r0+15 = proj_w * out
        float acc3[16];
        #pragma unroll
        for (int i = 0; i < 16; i++) acc3[i] = 0.0f;
        for (int cc = 0; cc < 64; cc += 16) {
            #pragma unroll
            for (int c = 0; c < 16; c++) {
                float ov = ols[cc + c][lane];
                #pragma unroll
                for (int i = 0; i < 16; i++) acc3[i] += Wp[i * 64 + cc + c] * ov;
            }
        }
        #pragma unroll
        for (int i = 0; i < 16; i++) yb[(size_t)(r0 + i) * NPIX + p] = acc3[i];
        // barrier at top of next iteration (after stage A) orders qls/ols reuse
    }
}

extern "C" void kernel_launch(void* const* d_in, const int* in_sizes, int n_in,
                              void* d_out, int out_size, void* d_ws, size_t ws_size,
                              hipStream_t stream) {
    const float* x      = (const float*)d_in[0];
    const float* qkv_w  = (const float*)d_in[1];
    const float* proj_w = (const float*)d_in[2];
    float* yout = (float*)d_out;
    float* kv   = (float*)d_ws;   // BATCH*NHEAD*HDIM*HDIM floats = 64 KB

    hipMemsetAsync(kv, 0, (size_t)BATCH * NHEAD * HDIM * HDIM * sizeof(float), stream);

    dim3 blk(256);
    la_pass1<<<dim3(BLOCKS_X, BATCH), blk, 0, stream>>>(x, qkv_w, kv);
    la_pass2<<<dim3(BLOCKS_X, BATCH), blk, 0, stream>>>(x, qkv_w, proj_w, kv, yout);
}

// Round 2
// 106.159 us; speedup vs baseline: 13.7025x; 13.7025x over previous
//
#include <hip/hip_runtime.h>
#include <hip/hip_bf16.h>

#define BATCH 8
#define CH    64
#define NPIX  65536
#define NHEAD 2
#define HDIM  32

typedef __attribute__((ext_vector_type(8))) short bf16x8;
typedef __attribute__((ext_vector_type(4))) float f32x4;

#define MFMA(a, b, c) __builtin_amdgcn_mfma_f32_16x16x32_bf16(a, b, c, 0, 0, 0)

// pack two f32 -> one u32 holding two bf16 (RNE)
__device__ __forceinline__ unsigned rne_pk(float lo, float hi) {
    unsigned ua = __float_as_uint(lo); ua += 0x7fffu + ((ua >> 16) & 1u);
    unsigned ub = __float_as_uint(hi); ub += 0x7fffu + ((ub >> 16) & 1u);
    return (ua >> 16) | (ub & 0xffff0000u);
}

__device__ __forceinline__ bf16x8 pack8(const float* f) {
    int4 iv;
    iv.x = (int)rne_pk(f[0], f[1]);
    iv.y = (int)rne_pk(f[2], f[3]);
    iv.z = (int)rne_pk(f[4], f[5]);
    iv.w = (int)rne_pk(f[6], f[7]);
    return *reinterpret_cast<bf16x8*>(&iv);
}

__device__ __forceinline__ float phi_f(float t) {
    return t > 0.0f ? t + 1.0f : __expf(t);
}

// A-layout fragment of row-major W[*][64]: lane gets (m = r0+l%16, k = k0+(l/16)*8+e)
// (identical lane data also serves as the B-frag of W^T)
__device__ __forceinline__ bf16x8 load_w_frag(const float* W, int r0, int k0, int lane) {
    const float* p = W + (size_t)(r0 + (lane & 15)) * 64 + k0 + ((lane >> 4) << 3);
    float f[8];
    #pragma unroll
    for (int e = 0; e < 8; e++) f[e] = p[e];
    return pack8(f);
}

// ---------------- Pass 1: KV[b][h][c][d] = sum_n phi(k)[c,n] v[d,n] ----------------
// grid (64, 8), block 256. Wave-independent 32-pixel strips; KV accum in MFMA C regs.
__global__ __launch_bounds__(256) void la_pass1(
    const float* __restrict__ x, const float* __restrict__ qkv_w,
    float* __restrict__ kv)
{
    __shared__ __align__(16) unsigned char smem[40960];

    const int tid  = threadIdx.x;
    const int lane = tid & 63;
    const int wv   = __builtin_amdgcn_readfirstlane(tid >> 6);
    const int b    = blockIdx.y;
    const int g    = lane >> 4;      // 0..3
    const int li   = lane & 15;

    // wave-private LDS: kls[64][40], vls[64][40] bf16 (row = channel, col = pixel; 80B rows)
    unsigned short* kls = (unsigned short*)(smem + wv * 10240);
    unsigned short* vls = kls + 64 * 40;

    // preload W^T B-frags for k|v output channels (qkv_w rows 64..191)
    bf16x8 Wf[8][2];
    #pragma unroll
    for (int j = 0; j < 8; j++)
        #pragma unroll
        for (int ks = 0; ks < 2; ks++)
            Wf[j][ks] = load_w_frag(qkv_w, 64 + 16 * j, 32 * ks, lane);

    f32x4 kvacc[2][2][2];  // [head][c-tile][d-tile]
    #pragma unroll
    for (int h = 0; h < 2; h++)
        #pragma unroll
        for (int mt = 0; mt < 2; mt++)
            #pragma unroll
            for (int nt = 0; nt < 2; nt++)
                kvacc[h][mt][nt] = (f32x4){0.f, 0.f, 0.f, 0.f};

    const float* xb = x + (size_t)b * CH * NPIX;

    for (int s = blockIdx.x * 4 + wv; s < 2048; s += 256) {
        const int px0 = s * 32;

        // ---- A-frags of X^T: (m = pixel, k = channel) straight from global
        bf16x8 xa[2][2];
        #pragma unroll
        for (int mt = 0; mt < 2; mt++) {
            const float* xp = xb + px0 + 16 * mt + li;
            #pragma unroll
            for (int ks = 0; ks < 2; ks++) {
                float f[8];
                #pragma unroll
                for (int e = 0; e < 8; e++)
                    f[e] = xp[(size_t)(32 * ks + 8 * g + e) * NPIX];
                xa[mt][ks] = pack8(f);
            }
        }

        // ---- GEMM1: (K|V)^T tiles = X^T * W^T; write packed [c][px] bf16 to LDS
        #pragma unroll
        for (int j = 0; j < 8; j++) {
            unsigned short* dst = (j < 4) ? kls : vls;
            const int crow = (j & 3) * 16 + li;
            #pragma unroll
            for (int mt = 0; mt < 2; mt++) {
                f32x4 acc = (f32x4){0.f, 0.f, 0.f, 0.f};
                acc = MFMA(xa[mt][0], Wf[j][0], acc);
                acc = MFMA(xa[mt][1], Wf[j][1], acc);
                float v0 = acc[0], v1 = acc[1], v2 = acc[2], v3 = acc[3];
                if (j < 4) { v0 = phi_f(v0); v1 = phi_f(v1); v2 = phi_f(v2); v3 = phi_f(v3); }
                // 4 values = 4 consecutive pixels (rows 4g+r), fixed channel crow
                *reinterpret_cast<uint2*>(dst + crow * 40 + 16 * mt + 4 * g) =
                    make_uint2(rne_pk(v0, v1), rne_pk(v2, v3));
            }
        }

        // ---- GEMM2: KV += phi_k * v^T  (K = 32 pixels of this strip)
        #pragma unroll
        for (int h = 0; h < 2; h++) {
            bf16x8 af[2], bv[2];
            #pragma unroll
            for (int mt = 0; mt < 2; mt++)
                af[mt] = *reinterpret_cast<const bf16x8*>(kls + (32 * h + 16 * mt + li) * 40 + 8 * g);
            #pragma unroll
            for (int nt = 0; nt < 2; nt++)
                bv[nt] = *reinterpret_cast<const bf16x8*>(vls + (32 * h + 16 * nt + li) * 40 + 8 * g);
            #pragma unroll
            for (int mt = 0; mt < 2; mt++)
                #pragma unroll
                for (int nt = 0; nt < 2; nt++)
                    kvacc[h][mt][nt] = MFMA(af[mt], bv[nt], kvacc[h][mt][nt]);
        }
    }

    // ---- block reduce (4 waves hold identical KV coverage) then atomics
    __syncthreads();
    float* rbuf = (float*)smem;  // [4][2048]
    #pragma unroll
    for (int h = 0; h < 2; h++)
        #pragma unroll
        for (int mt = 0; mt < 2; mt++)
            #pragma unroll
            for (int nt = 0; nt < 2; nt++) {
                const int t = (h * 2 + mt) * 2 + nt;
                #pragma unroll
                for (int r = 0; r < 4; r++)
                    rbuf[wv * 2048 + t * 256 + (4 * g + r) * 16 + li] = kvacc[h][mt][nt][r];
            }
    __syncthreads();

    float* kvb = kv + (size_t)b * NHEAD * HDIM * HDIM;
    for (int i = 0; i < 8; i++) {
        const int idx = i * 256 + tid;
        const float sum = rbuf[idx] + rbuf[2048 + idx] + rbuf[4096 + idx] + rbuf[6144 + idx];
        const int t = idx >> 8, within = idx & 255;
        const int row = within >> 4, col = within & 15;
        const int h = t >> 2, mt = (t >> 1) & 1, nt = t & 1;
        atomicAdd(&kvb[(h * 32 + 16 * mt + row) * 32 + 16 * nt + col], sum);
    }
}

// ---------------- Pass 2: y = proj * (KV^T * phi(q)) ----------------
// grid (128, 8), block 256. Wave-independent 16-pixel strips, zero barriers.
__global__ __launch_bounds__(256) void la_pass2(
    const float* __restrict__ x, const float* __restrict__ qkv_w,
    const float* __restrict__ proj_w, const float* __restrict__ kv,
    float* __restrict__ y)
{
    __shared__ __align__(16) unsigned short sm2[4][2][16][72];  // [wave][q|out][px][ch+pad]

    const int tid  = threadIdx.x;
    const int lane = tid & 63;
    const int wv   = __builtin_amdgcn_readfirstlane(tid >> 6);
    const int b    = blockIdx.y;
    const int g    = lane >> 4;
    const int li   = lane & 15;

    unsigned short* qT = &sm2[wv][0][0][0];
    unsigned short* oT = &sm2[wv][1][0][0];

    // preload A-frags: Wq, proj (row-major [o][c]), KV^T (from [b][h][c][d] f32)
    bf16x8 Aq[4][2], Ap[4][2], Akv[2][2];
    #pragma unroll
    for (int mt = 0; mt < 4; mt++)
        #pragma unroll
        for (int ks = 0; ks < 2; ks++) {
            Aq[mt][ks] = load_w_frag(qkv_w, 16 * mt, 32 * ks, lane);
            Ap[mt][ks] = load_w_frag(proj_w, 16 * mt, 32 * ks, lane);
        }
    const float* kvb = kv + (size_t)b * NHEAD * HDIM * HDIM;
    #pragma unroll
    for (int h = 0; h < 2; h++)
        #pragma unroll
        for (int mtd = 0; mtd < 2; mtd++) {
            float f[8];
            #pragma unroll
            for (int e = 0; e < 8; e++)
                f[e] = kvb[h * 1024 + (8 * g + e) * 32 + 16 * mtd + li];  // KV^T[d][c]=KV[c][d]
            Akv[h][mtd] = pack8(f);
        }

    const float* xb = x + (size_t)b * CH * NPIX;
    float*       yb = y + (size_t)b * CH * NPIX;

    for (int s = blockIdx.x * 4 + wv; s < 4096; s += 512) {
        const int px0 = s * 16;

        // ---- B-frags of x: (k = channel, n = pixel)
        bf16x8 bx[2];
        const float* xp = xb + px0 + li;
        #pragma unroll
        for (int ks = 0; ks < 2; ks++) {
            float f[8];
            #pragma unroll
            for (int e = 0; e < 8; e++)
                f[e] = xp[(size_t)(32 * ks + 8 * g + e) * NPIX];
            bx[ks] = pack8(f);
        }

        // ---- q = Wq * X, phi, packed store to qT[px][c]
        #pragma unroll
        for (int mt = 0; mt < 4; mt++) {
            f32x4 acc = (f32x4){0.f, 0.f, 0.f, 0.f};
            acc = MFMA(Aq[mt][0], bx[0], acc);
            acc = MFMA(Aq[mt][1], bx[1], acc);
            const float p0 = phi_f(acc[0]), p1 = phi_f(acc[1]);
            const float p2 = phi_f(acc[2]), p3 = phi_f(acc[3]);
            // 4 values = channels 16mt+4g..+3, fixed pixel li
            *reinterpret_cast<uint2*>(qT + li * 72 + 16 * mt + 4 * g) =
                make_uint2(rne_pk(p0, p1), rne_pk(p2, p3));
        }

        // ---- out = KV^T * q_phi per head, packed store to oT[px][32h+d]
        #pragma unroll
        for (int h = 0; h < 2; h++) {
            const bf16x8 bq = *reinterpret_cast<const bf16x8*>(qT + li * 72 + 32 * h + 8 * g);
            #pragma unroll
            for (int mtd = 0; mtd < 2; mtd++) {
                f32x4 acc = (f32x4){0.f, 0.f, 0.f, 0.f};
                acc = MFMA(Akv[h][mtd], bq, acc);
                *reinterpret_cast<uint2*>(oT + li * 72 + 32 * h + 16 * mtd + 4 * g) =
                    make_uint2(rne_pk(acc[0], acc[1]), rne_pk(acc[2], acc[3]));
            }
        }

        // ---- y = proj * out, store f32 (4x64B coalesced segments per row-group)
        const bf16x8 bo0 = *reinterpret_cast<const bf16x8*>(oT + li * 72 + 8 * g);
        const bf16x8 bo1 = *reinterpret_cast<const bf16x8*>(oT + li * 72 + 32 + 8 * g);
        #pragma unroll
        for (int mt = 0; mt < 4; mt++) {
            f32x4 acc = (f32x4){0.f, 0.f, 0.f, 0.f};
            acc = MFMA(Ap[mt][0], bo0, acc);
            acc = MFMA(Ap[mt][1], bo1, acc);
            #pragma unroll
            for (int r = 0; r < 4; r++)
                yb[(size_t)(16 * mt + 4 * g + r) * NPIX + px0 + li] = acc[r];
        }
    }
}

extern "C" void kernel_launch(void* const* d_in, const int* in_sizes, int n_in,
                              void* d_out, int out_size, void* d_ws, size_t ws_size,
                              hipStream_t stream) {
    (void)in_sizes; (void)n_in; (void)out_size; (void)ws_size;
    const float* x      = (const float*)d_in[0];
    const float* qkv_w  = (const float*)d_in[1];
    const float* proj_w = (const float*)d_in[2];
    float* yout = (float*)d_out;
    float* kv   = (float*)d_ws;  // 8*2*32*32 f32 = 32 KB

    hipMemsetAsync(kv, 0, (size_t)BATCH * NHEAD * HDIM * HDIM * sizeof(float), stream);

    la_pass1<<<dim3(64, BATCH), dim3(256), 0, stream>>>(x, qkv_w, kv);
    la_pass2<<<dim3(128, BATCH), dim3(256), 0, stream>>>(x, qkv_w, proj_w, kv, yout);
}